// Round 4
// baseline (1174.621 us; speedup 1.0000x reference)
//
#include <hip/hip_runtime.h>
#include <cstdint>
#include <cstddef>

#define BATCH 8
#define SEQ   4096
#define DS    512
#define JPL   8              // states per lane (64 lanes * 8 = 512)
#define BLK   4              // time steps per register block
#define NBLK  (SEQ / BLK)    // 1024 (even)
#define LN_EPS 1e-5f

typedef float v2f __attribute__((ext_vector_type(2)));
typedef float v4f __attribute__((ext_vector_type(4)));

static __device__ __forceinline__ v2f lo2(v4f x) { return __builtin_shufflevector(x, x, 0, 1); }
static __device__ __forceinline__ v2f hi2(v4f x) { return __builtin_shufflevector(x, x, 2, 3); }

// ---- DPP wave64 reduction: row_shr 1/2/4/8, row_bcast15/31 -> lane 63 ----
template <int CTRL>
__device__ __forceinline__ float dpp_add(float v) {
  int t = __builtin_amdgcn_update_dpp(0, __builtin_bit_cast(int, v), CTRL, 0xF, 0xF, true);
  return v + __builtin_bit_cast(float, t);
}
__device__ __forceinline__ float wave_sum64(float v) {
  v = dpp_add<0x111>(v);
  v = dpp_add<0x112>(v);
  v = dpp_add<0x114>(v);
  v = dpp_add<0x118>(v);
  v = dpp_add<0x142>(v);
  v = dpp_add<0x143>(v);
  return v;  // valid in lane 63
}
__device__ __forceinline__ float bcast63(float v) {
  return __builtin_bit_cast(float, __builtin_amdgcn_readlane(__builtin_bit_cast(int, v), 63));
}

// -------- single-wave-per-batch scan: no barriers, no LDS, all in registers --
// One 64-lane wave owns one batch row. x/vol double-buffered in VGPRs with
// one-block (4-step) prefetch distance; rg computed inline off-chain; readout
// reduced on-wave; out written directly (fused epilogue).
__global__ __launch_bounds__(64, 1) void ssm_scan(
    const float* __restrict__ x, const float* __restrict__ vol,
    const float* __restrict__ llr, const float* __restrict__ logb,
    const float* __restrict__ cvec, const float* __restrict__ lstp,
    const float* __restrict__ vgat, const float* __restrict__ lnw,
    const float* __restrict__ lnb, const float* __restrict__ alph,
    const float* __restrict__ logd, float* __restrict__ out)
{
  const int b    = blockIdx.x;
  const int lane = threadIdx.x;   // 0..63

  // ---- per-lane constants (8 states per lane) ----
  v2f bd[4], aw[4], ab[4], cw[4], cb[4], gate[4];
#pragma unroll
  for (int j = 0; j < JPL; ++j) {
    int n = lane * JPL + j;
    float lam = -expf(llr[n]);
    float st  = expf(lstp[n]);
    float z   = st * lam;
    float ad  = (2.0f + z) / (2.0f - z);
    float bdv = st * (1.0f + ad) * expf(logb[n]) * 0.5f;
    float wv  = lnw[n], bi = lnb[n], cv = cvec[n];
    bd[j >> 1][j & 1]   = bdv;
    aw[j >> 1][j & 1]   = ad * wv;
    ab[j >> 1][j & 1]   = ad * bi;
    gate[j >> 1][j & 1] = 1.0f / (1.0f + expf(-vgat[n]));
    cw[j >> 1][j & 1]   = cv * wv;   // c1 folded in below
    cb[j >> 1][j & 1]   = cv * bi;
  }
  float al   = 1.0f / (1.0f + expf(-alph[0]));
  float dd   = expf(logd[0]);
  float coef = __builtin_fmaf(1.0f - al, dd, al);  // al + (1-al)*d
  float c1   = 1.0f - al;
#pragma unroll
  for (int k = 0; k < 4; ++k) { cw[k] = cw[k] * c1; cb[k] = cb[k] * c1; }

  const float* xg = x   + (size_t)b * SEQ * DS + lane * JPL;
  float*       og = out + (size_t)b * SEQ * DS + lane * JPL;
  const float* vg = vol + (size_t)b * SEQ;

  v2f hp[4];
#pragma unroll
  for (int k = 0; k < 4; ++k) hp[k] = (v2f){0.0f, 0.0f};

  // register tiles: 4 steps x 8 floats/lane, double-buffered
  v4f XA[BLK][2], XB[BLK][2];
  v4f VA, VB;   // 4 vol scalars per block

  auto loadblk = [&](int blk, v4f (&X)[BLK][2], v4f& V) {
    const float* base = xg + (size_t)blk * BLK * DS;
#pragma unroll
    for (int u = 0; u < BLK; ++u) {
      X[u][0] = *(const v4f*)(base + u * DS);
      X[u][1] = *(const v4f*)(base + u * DS + 4);
    }
    V = *(const v4f*)(vg + blk * BLK);
  };

  auto procblk = [&](int blk, v4f (&X)[BLK][2], v4f& V) {
    float* ob = og + (size_t)blk * BLK * DS;
#pragma unroll
    for (int u = 0; u < BLK; ++u) {
      float vt = V[u];
      // gate reciprocal (off the recurrence chain; vol loaded a block ago)
      v2f rs[4];
#pragma unroll
      for (int k = 0; k < 4; ++k) {
        v2f den = gate[k] * vt + 1.0f;
        rs[k].x = __builtin_amdgcn_rcpf(den.x);
        rs[k].y = __builtin_amdgcn_rcpf(den.y);
      }
      v2f xs[4] = {lo2(X[u][0]), hi2(X[u][0]), lo2(X[u][1]), hi2(X[u][1])};

      v2f hr[4];
#pragma unroll
      for (int k = 0; k < 4; ++k)
        hr[k] = __builtin_elementwise_fma(bd[k], xs[k], hp[k]);  // hr = hp + bd*x

      // sum / sum-of-squares trees
      v2f t01 = hr[0] + hr[1], t23 = hr[2] + hr[3];
      v2f tt  = t01 + t23;
      float s1 = tt.x + tt.y;
      v2f m01 = hr[0] * hr[0];
      m01 = __builtin_elementwise_fma(hr[1], hr[1], m01);
      v2f m23 = hr[2] * hr[2];
      m23 = __builtin_elementwise_fma(hr[3], hr[3], m23);
      v2f mm = m01 + m23;
      float s2 = mm.x + mm.y;

      s1 = bcast63(wave_sum64(s1));
      s2 = bcast63(wave_sum64(s2));
      float mu  = s1 * (1.0f / DS);
      float m2e = __builtin_fmaf(s2, 1.0f / DS, LN_EPS);
      float var = __builtin_fmaf(-mu, mu, m2e);
      float inv = __builtin_amdgcn_rsqf(var);

      v2f muv = {mu, mu}, invv = {inv, inv};
      v2f u1 = {0.0f, 0.0f}, u3 = {0.0f, 0.0f};
#pragma unroll
      for (int k = 0; k < 4; ++k) {
        v2f hrm  = hr[k] - muv;
        v2f tv   = rs[k] * hrm;
        v2f sv   = aw[k] * tv;
        v2f abrs = ab[k] * rs[k];
        hp[k] = __builtin_elementwise_fma(invv, sv, abrs);   // next pending state
        u1 = __builtin_elementwise_fma(cw[k], tv, u1);       // readout partials
        u3 = __builtin_elementwise_fma(cb[k], rs[k], u3);
      }
      v2f dp = __builtin_elementwise_fma(u1, invv, u3);
      float dl = dp.x + dp.y;
      float s = bcast63(wave_sum64(dl));    // only delays the store, not the chain

      v4f o0 = X[u][0] * coef + s;
      v4f o1 = X[u][1] * coef + s;
      *(v4f*)(ob + (size_t)u * DS)     = o0;
      *(v4f*)(ob + (size_t)u * DS + 4) = o1;
    }
  };

  // ---- prologue: stage blocks 0 and 1 ----
  loadblk(0, XA, VA);
  loadblk(1, XB, VB);
  // ---- main loop: process k2 / k2+1, prefetch k2+2 / k2+3 ----
#pragma unroll 1
  for (int k2 = 0; k2 < NBLK; k2 += 2) {
    procblk(k2, XA, VA);
    if (k2 + 2 < NBLK) loadblk(k2 + 2, XA, VA);   // reg deps order this after reads
    procblk(k2 + 1, XB, VB);
    if (k2 + 3 < NBLK) loadblk(k2 + 3, XB, VB);
  }
}

extern "C" void kernel_launch(void* const* d_in, const int* in_sizes, int n_in,
                              void* d_out, int out_size, void* d_ws, size_t ws_size,
                              hipStream_t stream) {
  const float* x    = (const float*)d_in[0];   // [8,4096,512]
  const float* vol  = (const float*)d_in[1];   // [8,4096,1]
  const float* llr  = (const float*)d_in[2];   // [512]
  const float* logb = (const float*)d_in[3];   // [512,1]
  const float* cvec = (const float*)d_in[4];   // [1,512]
  const float* logd = (const float*)d_in[5];   // [1]
  const float* lstp = (const float*)d_in[6];   // [512]
  const float* vgat = (const float*)d_in[7];   // [512]
  const float* alph = (const float*)d_in[8];   // [1]
  const float* lnw  = (const float*)d_in[9];   // [512]
  const float* lnb  = (const float*)d_in[10];  // [512]
  float* outf = (float*)d_out;

  ssm_scan<<<BATCH, 64, 0, stream>>>(x, vol, llr, logb, cvec, lstp,
                                     vgat, lnw, lnb, alph, logd, outf);
}